// Round 6
// baseline (182.375 us; speedup 1.0000x reference)
//
#include <hip/hip_runtime.h>
#include <hip/hip_bf16.h>
#include <stdint.h>

#define BB     8
#define CC     320
#define NN     4096
#define SKV    77
#define HEADS  8
#define INNER  512
#define SCALE  0.125f

typedef float f32x4  __attribute__((ext_vector_type(4)));
typedef short bf16x8 __attribute__((ext_vector_type(8)));
typedef short s16x4  __attribute__((ext_vector_type(4)));

static __device__ __forceinline__ short f2bf(float f) {
  unsigned u = __float_as_uint(f);
  return (short)((u + 0x7fffu + ((u >> 16) & 1u)) >> 16);
}

// async global->LDS 16B copy; LDS dest is wave-uniform base + lane*16.
static __device__ __forceinline__ void gll16(void* lds, const void* g) {
  auto gp = reinterpret_cast<const uint32_t __attribute__((address_space(1)))*>(
      reinterpret_cast<uintptr_t>(g));
  auto lp = reinterpret_cast<uint32_t __attribute__((address_space(3)))*>(
      reinterpret_cast<uintptr_t>(lds));
  __builtin_amdgcn_global_load_lds(gp, lp, 16, 0, 0);
}

// ---------------------------------------------------------------------------
// prep: kv->bf16 | Wk,Wv,Wq(x SCALE),Wo tiled transposes | zero V_ws pad.
// blocks: [0,616) kv | [616,872) Wk/Wv | [872,912) Wq | [912,952) Wo |
// [952,1192) zero V_ws
// ---------------------------------------------------------------------------
__global__ __launch_bounds__(256) void prep_kernel(
    const float* __restrict__ kv, const float* __restrict__ Wk,
    const float* __restrict__ Wv, const float* __restrict__ Wq,
    const float* __restrict__ Wo, short* __restrict__ kv_bf,
    short* __restrict__ Wk_t, short* __restrict__ Wv_t,
    short* __restrict__ Wq_t, short* __restrict__ Wo_t,
    unsigned* __restrict__ zero_base) {
  __shared__ float T[64 * 65];
  const int blk = blockIdx.x, t = threadIdx.x;
  if (blk < 616) {
    const int base = blk * 1024;
    #pragma unroll
    for (int i = 0; i < 4; ++i) kv_bf[base + i*256 + t] = f2bf(kv[base + i*256 + t]);
    return;
  }
  if (blk >= 952) {              // zero V_ws (pad cols read by PV must be 0)
    const int base = (blk - 952) * 1024;
    #pragma unroll
    for (int i = 0; i < 4; ++i) zero_base[base + i*256 + t] = 0u;
    return;
  }
  const float* src; short* dst; int RS, CS, kt, ct; float scl = 1.0f;
  if (blk < 872) {               // Wk/Wv: [1024][512] -> [512][1024]
    const int tile = blk - 616;
    const bool isK = tile < 128;
    const int tt = isK ? tile : tile - 128;
    src = isK ? Wk : Wv; dst = isK ? Wk_t : Wv_t;
    RS = 1024; CS = 512; kt = tt >> 3; ct = tt & 7;
  } else if (blk < 912) {        // Wq: [320][512] -> [512][320], x SCALE
    const int tt = blk - 872;
    src = Wq; dst = Wq_t; RS = 320; CS = 512; kt = tt >> 3; ct = tt & 7;
    scl = SCALE;
  } else {                       // Wo: [512][320] -> [320][512]
    const int tt = blk - 912;
    src = Wo; dst = Wo_t; RS = 512; CS = 320; kt = tt / 5; ct = tt % 5;
  }
  const int cl = t & 63, rb = t >> 6;
  #pragma unroll
  for (int i = 0; i < 16; ++i)
    T[(rb + i*4)*65 + cl] = src[(size_t)(kt*64 + rb + i*4)*CS + ct*64 + cl];
  __syncthreads();
  #pragma unroll
  for (int i = 0; i < 16; ++i) {
    const int nl = rb + i*4;
    dst[(size_t)(ct*64 + nl)*RS + kt*64 + cl] = f2bf(T[cl*65 + nl] * scl);
  }
}

// ---------------------------------------------------------------------------
// kvproj: [616,1024]bf16 @ Wk_t/Wv_t -> K_ws [b][h][80][64], V_ws [b][h][64][96]
// ---------------------------------------------------------------------------
__global__ __launch_bounds__(256) void kvproj_kernel(
    const short* __restrict__ kv_bf, const short* __restrict__ Wk_t,
    const short* __restrict__ Wv_t, short* __restrict__ K_ws,
    short* __restrict__ V_ws) {
  const int t = threadIdx.x, w = t >> 6, lane = t & 63;
  const int l15 = lane & 15, q = lane >> 4;
  const int m0 = (blockIdx.x * 4 + w) * 16;
  const int y = blockIdx.y;
  const bool isK = (y < 8);
  const int h = y & 7;
  const short* __restrict__ Wt = isK ? Wk_t : Wv_t;
  const int arow = (m0 + l15 < 616) ? (m0 + l15) : 615;

  const f32x4 z = {0.f, 0.f, 0.f, 0.f};
  f32x4 acc[4] = {z, z, z, z};
  for (int k0 = 0; k0 < 1024; k0 += 32) {
    const bf16x8 a = *(const bf16x8*)(kv_bf + arow*1024 + k0 + q*8);
    #pragma unroll
    for (int nt = 0; nt < 4; ++nt) {
      const int n = h*64 + nt*16 + l15;
      const bf16x8 bfr = *(const bf16x8*)(Wt + n*1024 + k0 + q*8);
      acc[nt] = __builtin_amdgcn_mfma_f32_16x16x32_bf16(a, bfr, acc[nt], 0, 0, 0);
    }
  }
  #pragma unroll
  for (int nt = 0; nt < 4; ++nt) {
    const int d = nt*16 + l15;
    #pragma unroll
    for (int r = 0; r < 4; ++r) {
      const int row = m0 + q*4 + r;
      if (row < 616) {
        const int b = (int)(((unsigned)row * 54472u) >> 22);   // row/77
        const int s = row - b*77;
        if (isK) K_ws[((b*8 + h)*80 + s)*64 + d] = f2bf(acc[nt][r]);
        else     V_ws[((b*8 + h)*64 + d)*96 + s] = f2bf(acc[nt][r]);
      }
    }
  }
}

// ---------------------------------------------------------------------------
// fused v6 (v5 + staging-slot fix): 32 tokens/block, 4 waves, 1024 blocks,
// 3 blocks/CU (LDS 53,248 B) -> 12 waves/CU. Wave w owns cols
// [128w,128w+128) = heads {2w,2w+1}. K-loops wave-private + barrier-free.
// LDS (shorts): R_Q [0,16640) = Q/O tile [32][520]; A-panel [32][328]
//   aliases it during phase 0/1. Per-wave slice @16640+w*2560:
//   phase1 Wq half-stage (64r x 32k = 2048 sh, 256 slots),
//   phase2 P (16x104), phase3 Wo stage (80r x 32k = 2560 sh, 320 slots).
// ---------------------------------------------------------------------------
__global__ __launch_bounds__(256, 3) void fused_kernel(
    const float* __restrict__ query, const short* __restrict__ Wq_t,
    const short* __restrict__ K_ws, const short* __restrict__ V_ws,
    const short* __restrict__ Wo_t, const float* __restrict__ bo,
    float* __restrict__ out) {
  const int t = threadIdx.x, w = t >> 6, lane = t & 63;
  const int l15 = lane & 15, q = lane >> 4;
  const int b = blockIdx.x >> 7;
  const int n0 = (blockIdx.x & 127) * 32;

  __shared__ short S[26880];
  short* slice = S + 16640 + w * 2560;

  const f32x4 z = {0.f, 0.f, 0.f, 0.f};

  // ---------------- phase 0: query -> A-panel [32][328] bf16 -------------
  {
    const float* qb = query + (size_t)b * CC * NN + n0;
    #pragma unroll
    for (int i = 0; i < 10; ++i) {
      const int f = i * 256 + t;
      const int c = f >> 3, n4 = (f & 7) * 4;
      const f32x4 v = *(const f32x4*)(qb + (size_t)c * NN + n4);
      #pragma unroll
      for (int j = 0; j < 4; ++j)
        S[(n4 + j) * 328 + c] = f2bf(v[j]);
    }
  }

  // ---------------- phase 1: Q = A @ Wq^T (wave-private half-staging) ----
  {
    f32x4 acc[2][8];
    #pragma unroll
    for (int mt = 0; mt < 2; ++mt)
      #pragma unroll
      for (int nt = 0; nt < 8; ++nt) acc[mt][nt] = z;

    const short* __restrict__ Wqw = Wq_t + (size_t)(w * 128) * 320;
    auto stage1 = [&](int it, int h2) {   // 64 rows x 32k = 256 slots
      const int k0 = it * 32;
      #pragma unroll
      for (int p = 0; p < 4; ++p) {
        const int L = p * 64 + lane;
        gll16(slice + L * 8,
              Wqw + (size_t)(h2 * 64 + (L >> 2)) * 320 + k0 + (L & 3) * 8);
      }
    };

    stage1(0, 0);
    __syncthreads();   // barrier-1: A-panel ready (stage1(0,0) drains too)

    for (int it = 0; it < 10; ++it) {
      const int k0 = it * 32;
      asm volatile("s_waitcnt vmcnt(0)" ::: "memory");   // half-0 staged
      __builtin_amdgcn_sched_barrier(0);
      bf16x8 a[2], b0[4];
      #pragma unroll
      for (int mt = 0; mt < 2; ++mt)
        a[mt] = *(const bf16x8*)(S + (mt * 16 + l15) * 328 + k0 + q * 8);
      #pragma unroll
      for (int x = 0; x < 4; ++x)
        b0[x] = *(const bf16x8*)(slice + (x * 16 + l15) * 32 + q * 8);
      asm volatile("s_waitcnt lgkmcnt(0)" ::: "memory"); // reads landed
      __builtin_amdgcn_sched_barrier(0);
      stage1(it, 1);                                     // overwrite with half-1
      #pragma unroll
      for (int mt = 0; mt < 2; ++mt)
        #pragma unroll
        for (int x = 0; x < 4; ++x)
          acc[mt][x] = __builtin_amdgcn_mfma_f32_16x16x32_bf16(a[mt], b0[x], acc[mt][x], 0, 0, 0);

      asm volatile("s_waitcnt vmcnt(0)" ::: "memory");   // half-1 staged
      __builtin_amdgcn_sched_barrier(0);
      bf16x8 b1[4];
      #pragma unroll
      for (int x = 0; x < 4; ++x)
        b1[x] = *(const bf16x8*)(slice + (x * 16 + l15) * 32 + q * 8);
      asm volatile("s_waitcnt lgkmcnt(0)" ::: "memory");
      __builtin_amdgcn_sched_barrier(0);
      if (it + 1 < 10) stage1(it + 1, 0);
      #pragma unroll
      for (int mt = 0; mt < 2; ++mt)
        #pragma unroll
        for (int x = 0; x < 4; ++x)
          acc[mt][4 + x] = __builtin_amdgcn_mfma_f32_16x16x32_bf16(a[mt], b1[x], acc[mt][4 + x], 0, 0, 0);
    }
    __syncthreads();   // barrier-2: A dead everywhere; Q overlay legal
    #pragma unroll
    for (int mt = 0; mt < 2; ++mt)
      #pragma unroll
      for (int r = 0; r < 4; ++r) {
        const int tok = mt * 16 + q * 4 + r;
        #pragma unroll
        for (int nt = 0; nt < 8; ++nt)
          S[tok * 520 + w * 128 + nt * 16 + l15] = f2bf(acc[mt][nt][r]);
      }
  }
  // no barrier: wave w reads only its own Q columns + private slice.

  // ---------------- phase 2: attention (heads 2w,2w+1; 16-tok chunks) ----
  {
    short* scrw = slice;               // P: [16][104]
    #pragma unroll
    for (int i = 0; i < 2; ++i) {      // zero P cols [80,96)
      const int f = i * 64 + lane;     // 128 dwords
      *(unsigned*)(scrw + (f >> 3) * 104 + 80 + (f & 7) * 2) = 0u;
    }
    #pragma unroll
    for (int hh = 0; hh < 2; ++hh) {
      const int h = 2 * w + hh;
      const short* __restrict__ Kh = K_ws + (size_t)(b * 8 + h) * 80 * 64;
      const short* __restrict__ Vh = V_ws + (size_t)(b * 8 + h) * 64 * 96;
      for (int c16 = 0; c16 < 2; ++c16) {
        const int tb = c16 * 16;
        f32x4 qk[5];
        #pragma unroll
        for (int st = 0; st < 5; ++st) qk[st] = z;
        #pragma unroll
        for (int f = 0; f < 2; ++f) {
          const bf16x8 bq = *(const bf16x8*)(S + (tb + l15) * 520 + h * 64 + f * 32 + q * 8);
          #pragma unroll
          for (int st = 0; st < 5; ++st) {
            const bf16x8 a = *(const bf16x8*)(Kh + (st * 16 + l15) * 64 + f * 32 + q * 8);
            qk[st] = __builtin_amdgcn_mfma_f32_16x16x32_bf16(a, bq, qk[st], 0, 0, 0);
          }
        }
        float mx = -1e30f;
        #pragma unroll
        for (int st = 0; st < 5; ++st)
          #pragma unroll
          for (int r = 0; r < 4; ++r) {
            const int s = st * 16 + q * 4 + r;
            const float vv = (s < SKV) ? qk[st][r] : -1e30f;
            qk[st][r] = vv;
            mx = fmaxf(mx, vv);
          }
        mx = fmaxf(mx, __shfl_xor(mx, 16));
        mx = fmaxf(mx, __shfl_xor(mx, 32));
        float sum = 0.f;
        #pragma unroll
        for (int st = 0; st < 5; ++st)
          #pragma unroll
          for (int r = 0; r < 4; ++r) {
            const int s = st * 16 + q * 4 + r;
            const float e = (s < SKV) ? __expf(qk[st][r] - mx) : 0.f;
            qk[st][r] = e;
            sum += e;
          }
        sum += __shfl_xor(sum, 16);
        sum += __shfl_xor(sum, 32);
        const float inv = 1.0f / sum;
        #pragma unroll
        for (int st = 0; st < 5; ++st) {
          s16x4 pv;
          #pragma unroll
          for (int r = 0; r < 4; ++r) pv[r] = f2bf(qk[st][r] * inv);
          *(s16x4*)(scrw + l15 * 104 + st * 16 + q * 4) = pv;
        }
        f32x4 ov[4];
        #pragma unroll
        for (int dt = 0; dt < 4; ++dt) ov[dt] = z;
        #pragma unroll
        for (int f = 0; f < 3; ++f) {
          const bf16x8 bp = *(const bf16x8*)(scrw + l15 * 104 + f * 32 + q * 8);
          #pragma unroll
          for (int dt = 0; dt < 4; ++dt) {
            const bf16x8 a = *(const bf16x8*)(Vh + (dt * 16 + l15) * 96 + f * 32 + q * 8);
            ov[dt] = __builtin_amdgcn_mfma_f32_16x16x32_bf16(a, bp, ov[dt], 0, 0, 0);
          }
        }
        // O overwrites Q in place (own cols; this chunk's Q already consumed)
        #pragma unroll
        for (int dt = 0; dt < 4; ++dt) {
          s16x4 pv;
          #pragma unroll
          for (int r = 0; r < 4; ++r) pv[r] = f2bf(ov[dt][r]);
          *(s16x4*)(S + (tb + l15) * 520 + h * 64 + dt * 16 + q * 4) = pv;
        }
      }
    }
  }

  // ---------------- phase 3: out = Wo_t @ O^T + bias (wave-private) ------
  {
    f32x4 oc[5][2];
    #pragma unroll
    for (int mt = 0; mt < 5; ++mt)
      #pragma unroll
      for (int nt = 0; nt < 2; ++nt) oc[mt][nt] = z;

    const short* __restrict__ Wow = Wo_t + (size_t)(w * 80) * 512;
    auto stage3 = [&](int it) {          // 80 rows x 32k = 320 slots
      const int k0 = it * 32;
      #pragma unroll
      for (int p = 0; p < 5; ++p) {
        const int L = p * 64 + lane;
        gll16(slice + L * 8, Wow + (size_t)(L >> 2) * 512 + k0 + (L & 3) * 8);
      }
    };

    stage3(0);         // issue before barrier; staging overlaps the wait
    __syncthreads();   // barrier-3: all O written
    for (int it = 0; it < 16; ++it) {
      const int k0 = it * 32;
      asm volatile("s_waitcnt vmcnt(0)" ::: "memory");
      __builtin_amdgcn_sched_barrier(0);
      bf16x8 a[5], bb[2];
      #pragma unroll
      for (int mt = 0; mt < 5; ++mt)
        a[mt] = *(const bf16x8*)(slice + (mt * 16 + l15) * 32 + q * 8);
      #pragma unroll
      for (int nt = 0; nt < 2; ++nt)
        bb[nt] = *(const bf16x8*)(S + (nt * 16 + l15) * 520 + k0 + q * 8);
      asm volatile("s_waitcnt lgkmcnt(0)" ::: "memory");
      __builtin_amdgcn_sched_barrier(0);
      if (it + 1 < 16) stage3(it + 1);
      #pragma unroll
      for (int mt = 0; mt < 5; ++mt)
        #pragma unroll
        for (int nt = 0; nt < 2; ++nt)
          oc[mt][nt] = __builtin_amdgcn_mfma_f32_16x16x32_bf16(a[mt], bb[nt], oc[mt][nt], 0, 0, 0);
    }
    #pragma unroll
    for (int mt = 0; mt < 5; ++mt)
      #pragma unroll
      for (int r = 0; r < 4; ++r) {
        const int c = w * 80 + mt * 16 + q * 4 + r;
        const float bv = bo[c];
        float* rowp = out + ((size_t)(b * CC + c)) * NN + n0;
        #pragma unroll
        for (int nt = 0; nt < 2; ++nt)
          rowp[nt * 16 + l15] = oc[mt][nt][r] + bv;
      }
  }
}

// ---------------------------------------------------------------------------
extern "C" void kernel_launch(void* const* d_in, const int* in_sizes, int n_in,
                              void* d_out, int out_size, void* d_ws, size_t ws_size,
                              hipStream_t stream) {
  const float* query = (const float*)d_in[0];
  const float* kv    = (const float*)d_in[1];
  const float* Wq    = (const float*)d_in[2];
  const float* Wk    = (const float*)d_in[3];
  const float* Wv    = (const float*)d_in[4];
  const float* Wo    = (const float*)d_in[5];
  const float* bo    = (const float*)d_in[6];
  float* out = (float*)d_out;

  char* p = (char*)d_ws;
  short* K_ws  = (short*)(p);             //   819,200 B [8][8][80][64]
  short* V_ws  = (short*)(p +   819200);  //   983,040 B [8][8][64][96]
  short* Wq_t  = (short*)(p +  1802240);  //   327,680 B [512][320] (x SCALE)
  short* Wo_t  = (short*)(p +  2129920);  //   327,680 B [320][512]
  short* kv_bf = (short*)(p +  2457600);  //  1,261,568 B [616][1024]
  short* Wk_t  = (short*)(p +  3719168);  //  1,048,576 B [512][1024]
  short* Wv_t  = (short*)(p +  4767744);  //  1,048,576 B [512][1024]

  prep_kernel<<<1192, 256, 0, stream>>>(kv, Wk, Wv, Wq, Wo, kv_bf,
                                        Wk_t, Wv_t, Wq_t, Wo_t,
                                        (unsigned*)V_ws);
  kvproj_kernel<<<dim3(10, 16), 256, 0, stream>>>(kv_bf, Wk_t, Wv_t, K_ws, V_ws);
  fused_kernel<<<1024, 256, 0, stream>>>(query, Wq_t, K_ws, V_ws, Wo_t, bo, out);
}